// Round 22
// baseline (303.503 us; speedup 1.0000x reference)
//
#include <hip/hip_runtime.h>
#include <hip/hip_bf16.h>

// RGCN 2-layer forward. Transform-then-aggregate on BOTH layers.
// L1: Y[n,0:1152] = bf16(x[n]) @ [W_r0..W_r7 | Wroot]  (dense bf16 MFMA GEMM,
//     operand-swapped). 1-wave blocks (64 thr, grid 3128) + NON-TEMPORAL Y
//     stores (u64 path; keeps W/x L2-resident; Y is a write-once stream).
//     W hi+lo triple-buffered (2-kstep lead). 576 MFMA/wave.
// Sort: counting sort -> ei2[pos] = {src*8+rel, bits(1/cnt)} (mean folded/edge).
// hgather: per-node flat edge loop, 4-deep unrolled; fused layer-2 transform.
// out2: 8 lanes/node (lane=relation), scale pre-folded.

#define NR 8
#define DH 128

typedef short short8 __attribute__((ext_vector_type(8)));
typedef float f32x4 __attribute__((ext_vector_type(4)));

__device__ inline ushort f2bf(float v) {
  __hip_bfloat16 b = __float2bfloat16(v);
  return *reinterpret_cast<ushort*>(&b);
}
__device__ inline float bf2f(ushort u) {
  __hip_bfloat16 b;
  *reinterpret_cast<ushort*>(&b) = u;
  return __bfloat162float(b);
}
__device__ inline uint pk2(float lo, float hi) {
  return (uint)f2bf(lo) | ((uint)f2bf(hi) << 16);
}
union U128 { uint4 u; short8 s; };
union FU { float f; int i; };

// ---------- counting sort ----------
__global__ __launch_bounds__(256) void k_hist(const int* __restrict__ dst, const int* __restrict__ et,
                                              int* __restrict__ hist, int E) {
  int e = blockIdx.x * 256 + threadIdx.x;
  if (e < E) atomicAdd(&hist[dst[e] * NR + et[e]], 1);
}

__global__ __launch_bounds__(256) void k_scan_local(const int* __restrict__ hist, int* __restrict__ offs,
                                                    int* __restrict__ blksum, int S) {
  __shared__ int tsum[256];
  int tid = threadIdx.x;
  int base = blockIdx.x * 1024 + tid * 4;
  int v[4], tot = 0;
  #pragma unroll
  for (int i = 0; i < 4; i++) { v[i] = (base + i < S) ? hist[base + i] : 0; tot += v[i]; }
  tsum[tid] = tot;
  __syncthreads();
  for (int off = 1; off < 256; off <<= 1) {
    int val = tsum[tid];
    int add = (tid >= off) ? tsum[tid - off] : 0;
    __syncthreads();
    tsum[tid] = val + add;
    __syncthreads();
  }
  int run = tsum[tid] - tot;
  #pragma unroll
  for (int i = 0; i < 4; i++) {
    if (base + i < S) offs[base + i] = run;
    run += v[i];
  }
  if (tid == 255) blksum[blockIdx.x] = tsum[255];
}

__global__ __launch_bounds__(512) void k_scan_blk(const int* __restrict__ blksum, int* __restrict__ blkoff, int NB) {
  __shared__ int s[512];
  int tid = threadIdx.x;
  int v = (tid < NB) ? blksum[tid] : 0;
  s[tid] = v;
  __syncthreads();
  for (int off = 1; off < 512; off <<= 1) {
    int val = s[tid];
    int add = (tid >= off) ? s[tid - off] : 0;
    __syncthreads();
    s[tid] = val + add;
    __syncthreads();
  }
  if (tid < NB) blkoff[tid] = s[tid] - v;
}

__global__ __launch_bounds__(256) void k_scan_add(int* __restrict__ offs, const int* __restrict__ blkoff, int S) {
  int tid = threadIdx.x;
  int base = blockIdx.x * 1024 + tid * 4;
  int add = blkoff[blockIdx.x];
  #pragma unroll
  for (int i = 0; i < 4; i++)
    if (base + i < S) offs[base + i] += add;
}

// scatter: ei2[pos] = {src*8+rel, bits(1/cnt)}; offs[seg] becomes segment END
__global__ __launch_bounds__(256) void k_scatter_idx(const int* __restrict__ src, const int* __restrict__ dst,
                                                     const int* __restrict__ et, const int* __restrict__ hist,
                                                     int* __restrict__ offs, int2* __restrict__ ei2, int E) {
  int e = blockIdx.x * 256 + threadIdx.x;
  if (e >= E) return;
  int r = et[e];
  int seg = dst[e] * NR + r;
  int pos = atomicAdd(&offs[seg], 1);
  FU sc;
  sc.f = 1.f / fmaxf((float)hist[seg], 1.f);
  ei2[pos] = make_int2(src[e] * NR + r, sc.i);
}

// ---------- W split+transpose: Wt[c][k], c in [0,1152), k in [0,128) ----------
__global__ __launch_bounds__(128) void k_wsplit(const float* __restrict__ W1, const float* __restrict__ Wr1,
                                                ushort* __restrict__ WtH, ushort* __restrict__ WtL) {
  int c = blockIdx.x;          // 0..1151
  int k = threadIdx.x;         // 0..127
  float v;
  if (c < 1024) {
    int r = c >> 7, col = c & 127;
    v = W1[((size_t)r * 128 + k) * 128 + col];
  } else {
    v = Wr1[(size_t)k * 128 + (c - 1024)];
  }
  ushort hi = f2bf(v);
  ushort lo = f2bf(v - bf2f(hi));
  WtH[(size_t)c * 128 + k] = hi;
  WtL[(size_t)c * 128 + k] = lo;
}

// ---------- dense GEMM: Y[N,1152] = bf16(x[N,128]) @ Wt^T, bf16 out ----------
// Operand swap: D = mfma(A=Wfrag, B=xfrag) -> D[row=Y-col][col=node].
// 1-WAVE BLOCKS: 64 thr; blockIdx.x = nodeblk*4 + panel; wave owns 288 cols.
// x cast f32->bf16 in prologue into xbr[4][4] (register-resident).
// W hi+lo triple-buffered (pw0/1/2, 2-kstep lead). Y stores NON-TEMPORAL via
// u64 (write-once stream; keeps W/x resident in L2). Barrier-free, no LDS.
__global__ __launch_bounds__(64) void k_gemm_dense(
    const float* __restrict__ x,
    const ushort* __restrict__ WtH, const ushort* __restrict__ WtL,
    ushort* __restrict__ Y, int N) {
  int lane = threadIdx.x;
  int n0 = (blockIdx.x >> 2) * 64;
  int wbase = (blockIdx.x & 3) * 288;

  int frow = lane & 15;
  int fk8 = (lane >> 4) * 8;
  int q4 = (lane >> 4) * 4;

  int anode[4];
  bool nodeok[4];
  size_t ybase[4];
  #pragma unroll
  for (int nf = 0; nf < 4; nf++) {
    int n = n0 + nf * 16 + frow;
    nodeok[nf] = (n < N);
    anode[nf] = nodeok[nf] ? n : (N - 1);
    ybase[nf] = (size_t)anode[nf] * 1152 + q4;
  }

  uint4 xbr[4][4];
  #pragma unroll
  for (int nf = 0; nf < 4; nf++) {
    #pragma unroll
    for (int kc = 0; kc < 4; kc++) {
      const float4* xp = (const float4*)(x + (size_t)anode[nf] * 128 + kc * 32 + fk8);
      float4 v0 = xp[0], v1 = xp[1];
      uint4 o;
      o.x = pk2(v0.x, v0.y);
      o.y = pk2(v0.z, v0.w);
      o.z = pk2(v1.x, v1.y);
      o.w = pk2(v1.z, v1.w);
      xbr[nf][kc] = o;
    }
  }

  f32x4 acc[2][4];
  uint4 pw0[2][2], pw1[2][2], pw2[2][2];  // W frags [cf][plane], triple-buffered

  #define LOADW(P, CB, KC)                                                     \
    {                                                                          \
      _Pragma("unroll")                                                        \
      for (int cf = 0; cf < 2; cf++) {                                         \
        int c_ = (CB) + cf * 16 + frow;                                        \
        P[cf][0] = *(const uint4*)(WtH + (size_t)c_ * 128 + (KC) * 32 + fk8);  \
        P[cf][1] = *(const uint4*)(WtL + (size_t)c_ * 128 + (KC) * 32 + fk8);  \
      }                                                                        \
    }
  #define KSTEP(KC, PWU)                                                       \
    {                                                                          \
      _Pragma("unroll")                                                        \
      for (int cf = 0; cf < 2; cf++) {                                         \
        U128 wh_, wl_;                                                         \
        wh_.u = PWU[cf][0];                                                    \
        wl_.u = PWU[cf][1];                                                    \
        _Pragma("unroll")                                                      \
        for (int nf = 0; nf < 4; nf++) {                                       \
          U128 xv_;                                                            \
          xv_.u = xbr[nf][KC];                                                 \
          acc[cf][nf] = __builtin_amdgcn_mfma_f32_16x16x32_bf16(wh_.s, xv_.s, acc[cf][nf], 0, 0, 0); \
          acc[cf][nf] = __builtin_amdgcn_mfma_f32_16x16x32_bf16(wl_.s, xv_.s, acc[cf][nf], 0, 0, 0); \
        }                                                                      \
      }                                                                        \
    }
  // Entry invariant: X0 = CB.k0, X1 = CB.k1 already loaded (2-kstep lead).
  #define CHUNK(CB, NCB, X0, X1, X2, ISLAST)                                   \
    {                                                                          \
      _Pragma("unroll")                                                        \
      for (int cf = 0; cf < 2; cf++)                                           \
        _Pragma("unroll")                                                      \
        for (int nf = 0; nf < 4; nf++) acc[cf][nf] = (f32x4){0.f, 0.f, 0.f, 0.f}; \
      LOADW(X2, CB, 2);                                                        \
      KSTEP(0, X0);                                                            \
      LOADW(X0, CB, 3);                                                        \
      KSTEP(1, X1);                                                            \
      if (!(ISLAST)) { LOADW(X1, NCB, 0); }                                    \
      KSTEP(2, X2);                                                            \
      if (!(ISLAST)) { LOADW(X2, NCB, 1); }                                    \
      KSTEP(3, X0);                                                            \
      _Pragma("unroll")                                                        \
      for (int cf = 0; cf < 2; cf++)                                           \
        _Pragma("unroll")                                                      \
        for (int nf = 0; nf < 4; nf++) {                                       \
          if (nodeok[nf]) {                                                    \
            unsigned long long o_ =                                            \
                (unsigned long long)f2bf(acc[cf][nf][0]) |                     \
                ((unsigned long long)f2bf(acc[cf][nf][1]) << 16) |             \
                ((unsigned long long)f2bf(acc[cf][nf][2]) << 32) |             \
                ((unsigned long long)f2bf(acc[cf][nf][3]) << 48);              \
            __builtin_nontemporal_store(                                       \
                o_, (unsigned long long*)(Y + ybase[nf] + (CB) + cf * 16));    \
          }                                                                    \
        }                                                                      \
    }

  LOADW(pw0, wbase, 0);
  LOADW(pw1, wbase, 1);

  CHUNK(wbase + 0,   wbase + 32,  pw0, pw1, pw2, 0)
  CHUNK(wbase + 32,  wbase + 64,  pw1, pw2, pw0, 0)
  CHUNK(wbase + 64,  wbase + 96,  pw2, pw0, pw1, 0)
  CHUNK(wbase + 96,  wbase + 128, pw0, pw1, pw2, 0)
  CHUNK(wbase + 128, wbase + 160, pw1, pw2, pw0, 0)
  CHUNK(wbase + 160, wbase + 192, pw2, pw0, pw1, 0)
  CHUNK(wbase + 192, wbase + 224, pw0, pw1, pw2, 0)
  CHUNK(wbase + 224, wbase + 256, pw1, pw2, pw0, 0)
  CHUNK(wbase + 256, 0,           pw2, pw0, pw1, 1)

  #undef LOADW
  #undef KSTEP
  #undef CHUNK
}

// ---------- fused flat h-gather + layer-2 transform ----------
__global__ __launch_bounds__(256) void k_hgather(const int* __restrict__ offs, const int* __restrict__ hist,
                                                 const int2* __restrict__ ei2, const ushort* __restrict__ Y,
                                                 const float* __restrict__ b1,
                                                 const float* __restrict__ W2, const float* __restrict__ Wr2,
                                                 float* __restrict__ t, int N) {
  __shared__ float Wt[18 * 128];
  int tid = threadIdx.x;
  for (int i = tid; i < 2304; i += 256) {
    float v; int oc, d;
    if (i < 2048) { int r = i >> 8, rem = i & 255; d = rem >> 1; int c = rem & 1; oc = r * 2 + c; v = W2[i]; }
    else { int i2 = i - 2048; d = i2 >> 1; int c = i2 & 1; oc = 16 + c; v = Wr2[i2]; }
    Wt[oc * 128 + d] = v;
  }
  __syncthreads();

  int node = blockIdx.x * 4 + (tid >> 6);
  int lane = tid & 63;
  if (node >= N) return;
  int c0 = lane * 2;
  int seg0 = node * NR;
  int st = offs[seg0] - hist[seg0];
  int en = offs[seg0 + 7];

  uint vroot = *(const uint*)(Y + (size_t)node * 1152 + 1024 + c0);
  float2 bb = *(const float2*)(b1 + c0);
  float ax = bf2f((ushort)(vroot & 0xffff)) + bb.x;
  float ay = bf2f((ushort)(vroot >> 16)) + bb.y;

  int i = st;
  for (; i + 4 <= en; i += 4) {
    int2 e0 = ei2[i + 0];
    int2 e1 = ei2[i + 1];
    int2 e2 = ei2[i + 2];
    int2 e3 = ei2[i + 3];
    uint y0 = ((uint)(e0.x + (e0.x >> 3)) << 7) + c0;
    uint y1 = ((uint)(e1.x + (e1.x >> 3)) << 7) + c0;
    uint y2 = ((uint)(e2.x + (e2.x >> 3)) << 7) + c0;
    uint y3 = ((uint)(e3.x + (e3.x >> 3)) << 7) + c0;
    uint v0 = *(const uint*)(Y + y0);
    uint v1 = *(const uint*)(Y + y1);
    uint v2 = *(const uint*)(Y + y2);
    uint v3 = *(const uint*)(Y + y3);
    FU s0, s1, s2, s3;
    s0.i = e0.y; s1.i = e1.y; s2.i = e2.y; s3.i = e3.y;
    ax += bf2f((ushort)(v0 & 0xffff)) * s0.f + bf2f((ushort)(v1 & 0xffff)) * s1.f +
          bf2f((ushort)(v2 & 0xffff)) * s2.f + bf2f((ushort)(v3 & 0xffff)) * s3.f;
    ay += bf2f((ushort)(v0 >> 16)) * s0.f + bf2f((ushort)(v1 >> 16)) * s1.f +
          bf2f((ushort)(v2 >> 16)) * s2.f + bf2f((ushort)(v3 >> 16)) * s3.f;
  }
  for (; i < en; i++) {
    int2 e = ei2[i];
    uint yo = ((uint)(e.x + (e.x >> 3)) << 7) + c0;
    uint v = *(const uint*)(Y + yo);
    FU sc; sc.i = e.y;
    ax += bf2f((ushort)(v & 0xffff)) * sc.f;
    ay += bf2f((ushort)(v >> 16)) * sc.f;
  }

  float hx = fmaxf(ax, 0.f);
  float hy = fmaxf(ay, 0.f);

  #pragma unroll
  for (int oc = 0; oc < 18; oc++) {
    float2 wv = *(const float2*)(Wt + oc * 128 + c0);
    float p = hx * wv.x + hy * wv.y;
    p += __shfl_xor(p, 32); p += __shfl_xor(p, 16); p += __shfl_xor(p, 8);
    p += __shfl_xor(p, 4);  p += __shfl_xor(p, 2);  p += __shfl_xor(p, 1);
    if (lane == 0) t[(size_t)node * 18 + oc] = p;
  }
}

// ---------- output: 8 lanes per node (lane = relation), scale pre-folded ----------
__global__ __launch_bounds__(256) void k_out2(const int* __restrict__ offs, const int* __restrict__ hist,
                                              const int2* __restrict__ ei2, const float* __restrict__ t,
                                              const float* __restrict__ b2, float* __restrict__ out, int N) {
  int tid = threadIdx.x;
  int node = blockIdx.x * 32 + (tid >> 3);
  int r = tid & 7;
  if (node >= N) return;
  int seg = node * NR + r;
  int en = offs[seg];
  int cc = hist[seg];
  float s0 = 0.f, s1 = 0.f;
  for (int i = en - cc; i < en; i++) {
    int2 e = ei2[i];
    int src = e.x >> 3;
    FU sc; sc.i = e.y;
    float2 tv = *(const float2*)(t + (size_t)src * 18 + r * 2);
    s0 += tv.x * sc.f;
    s1 += tv.y * sc.f;
  }
  s0 += __shfl_xor(s0, 1); s1 += __shfl_xor(s1, 1);
  s0 += __shfl_xor(s0, 2); s1 += __shfl_xor(s1, 2);
  s0 += __shfl_xor(s0, 4); s1 += __shfl_xor(s1, 4);
  if (r == 0) {
    out[(size_t)node * 2 + 0] = s0 + t[(size_t)node * 18 + 16] + b2[0];
    out[(size_t)node * 2 + 1] = s1 + t[(size_t)node * 18 + 17] + b2[1];
  }
}

extern "C" void kernel_launch(void* const* d_in, const int* in_sizes, int n_in,
                              void* d_out, int out_size, void* d_ws, size_t ws_size,
                              hipStream_t stream) {
  const float* x   = (const float*)d_in[0];
  const int*   ei  = (const int*)d_in[1];
  const int*   et  = (const int*)d_in[2];
  const float* W1  = (const float*)d_in[3];
  const float* Wr1 = (const float*)d_in[4];
  const float* b1  = (const float*)d_in[5];
  const float* W2  = (const float*)d_in[6];
  const float* Wr2 = (const float*)d_in[7];
  const float* b2  = (const float*)d_in[8];
  float* out = (float*)d_out;

  int E = in_sizes[1] / 2;
  int N = in_sizes[0] / DH;
  int S = N * NR;
  const int* src = ei;
  const int* dst = ei + E;

  // ws layout: ints | ei2 (int2, E) | WtH WtL | Y (bf16, N*1152) | t
  int* hist       = (int*)d_ws;                  // S
  int* offs       = hist + S;                    // S
  int* blksum     = offs + S;                    // 1024
  int* blkoff     = blksum + 1024;               // 1024
  int2* ei2       = (int2*)(blkoff + 1024);      // E int2 (8B-aligned)
  size_t int_elems = (size_t)S * 2 + 2048 + (size_t)E * 2;
  int_elems = (int_elems + 3) & ~(size_t)3;      // 16B align
  ushort* WtH = (ushort*)(hist + int_elems);     // 1152*128
  ushort* WtL = WtH + 1152 * 128;                // 1152*128
  ushort* Y   = WtL + 1152 * 128;                // N*1152
  size_t ush_elems = 2 * 1152 * 128 + (size_t)N * 1152;
  ush_elems = (ush_elems + 1) & ~(size_t)1;      // float align
  float* t = (float*)(WtH + ush_elems);          // N*18

  hipMemsetAsync(hist, 0, sizeof(int) * (size_t)S, stream);

  k_hist<<<(E + 255) / 256, 256, 0, stream>>>(dst, et, hist, E);

  int NB = (S + 1023) / 1024;
  k_scan_local<<<NB, 256, 0, stream>>>(hist, offs, blksum, S);
  k_scan_blk<<<1, 512, 0, stream>>>(blksum, blkoff, NB);
  k_scan_add<<<NB, 256, 0, stream>>>(offs, blkoff, S);

  k_scatter_idx<<<(E + 255) / 256, 256, 0, stream>>>(src, dst, et, hist, offs, ei2, E);

  k_wsplit<<<1152, 128, 0, stream>>>(W1, Wr1, WtH, WtL);

  int nblk = (N + 63) / 64;
  k_gemm_dense<<<nblk * 4, 64, 0, stream>>>(x, WtH, WtL, Y, N);

  k_hgather<<<(N + 3) / 4, 256, 0, stream>>>(offs, hist, ei2, Y, b1, W2, Wr2, t, N);

  k_out2<<<(N + 31) / 32, 256, 0, stream>>>(offs, hist, ei2, t, b2, out, N);
}

// Round 23
// 280.875 us; speedup vs baseline: 1.0806x; 1.0806x over previous
//
#include <hip/hip_runtime.h>
#include <hip/hip_bf16.h>

// RGCN 2-layer forward. Transform-then-aggregate on BOTH layers.
// L1: Y[n,0:1152] = bf16(x[n]) @ [W_r0..W_r7 | Wroot]  (dense bf16 MFMA GEMM,
//     operand-swapped, r18 geometry: 782 blocks x 4 waves x 288 cols,
//     576 MFMA/wave, W hi+lo double-buffered, regular ushort4 stores).
// Sort: counting sort -> ei2[pos] = {src*8+rel, bits(1/cnt)} (mean folded/edge).
// hgather: per-node flat edge loop, 8-DEEP unrolled (8 Y loads in flight);
//     fused layer-2 transform -> t[n,0:18].
// out2: 8 lanes/node (lane=relation), scale pre-folded.

#define NR 8
#define DH 128

typedef short short8 __attribute__((ext_vector_type(8)));
typedef float f32x4 __attribute__((ext_vector_type(4)));

__device__ inline ushort f2bf(float v) {
  __hip_bfloat16 b = __float2bfloat16(v);
  return *reinterpret_cast<ushort*>(&b);
}
__device__ inline float bf2f(ushort u) {
  __hip_bfloat16 b;
  *reinterpret_cast<ushort*>(&b) = u;
  return __bfloat162float(b);
}
__device__ inline uint pk2(float lo, float hi) {
  return (uint)f2bf(lo) | ((uint)f2bf(hi) << 16);
}
union U128 { uint4 u; short8 s; };
union FU { float f; int i; };

// ---------- counting sort ----------
__global__ __launch_bounds__(256) void k_hist(const int* __restrict__ dst, const int* __restrict__ et,
                                              int* __restrict__ hist, int E) {
  int e = blockIdx.x * 256 + threadIdx.x;
  if (e < E) atomicAdd(&hist[dst[e] * NR + et[e]], 1);
}

__global__ __launch_bounds__(256) void k_scan_local(const int* __restrict__ hist, int* __restrict__ offs,
                                                    int* __restrict__ blksum, int S) {
  __shared__ int tsum[256];
  int tid = threadIdx.x;
  int base = blockIdx.x * 1024 + tid * 4;
  int v[4], tot = 0;
  #pragma unroll
  for (int i = 0; i < 4; i++) { v[i] = (base + i < S) ? hist[base + i] : 0; tot += v[i]; }
  tsum[tid] = tot;
  __syncthreads();
  for (int off = 1; off < 256; off <<= 1) {
    int val = tsum[tid];
    int add = (tid >= off) ? tsum[tid - off] : 0;
    __syncthreads();
    tsum[tid] = val + add;
    __syncthreads();
  }
  int run = tsum[tid] - tot;
  #pragma unroll
  for (int i = 0; i < 4; i++) {
    if (base + i < S) offs[base + i] = run;
    run += v[i];
  }
  if (tid == 255) blksum[blockIdx.x] = tsum[255];
}

__global__ __launch_bounds__(512) void k_scan_blk(const int* __restrict__ blksum, int* __restrict__ blkoff, int NB) {
  __shared__ int s[512];
  int tid = threadIdx.x;
  int v = (tid < NB) ? blksum[tid] : 0;
  s[tid] = v;
  __syncthreads();
  for (int off = 1; off < 512; off <<= 1) {
    int val = s[tid];
    int add = (tid >= off) ? s[tid - off] : 0;
    __syncthreads();
    s[tid] = val + add;
    __syncthreads();
  }
  if (tid < NB) blkoff[tid] = s[tid] - v;
}

__global__ __launch_bounds__(256) void k_scan_add(int* __restrict__ offs, const int* __restrict__ blkoff, int S) {
  int tid = threadIdx.x;
  int base = blockIdx.x * 1024 + tid * 4;
  int add = blkoff[blockIdx.x];
  #pragma unroll
  for (int i = 0; i < 4; i++)
    if (base + i < S) offs[base + i] += add;
}

// scatter: ei2[pos] = {src*8+rel, bits(1/cnt)}; offs[seg] becomes segment END
__global__ __launch_bounds__(256) void k_scatter_idx(const int* __restrict__ src, const int* __restrict__ dst,
                                                     const int* __restrict__ et, const int* __restrict__ hist,
                                                     int* __restrict__ offs, int2* __restrict__ ei2, int E) {
  int e = blockIdx.x * 256 + threadIdx.x;
  if (e >= E) return;
  int r = et[e];
  int seg = dst[e] * NR + r;
  int pos = atomicAdd(&offs[seg], 1);
  FU sc;
  sc.f = 1.f / fmaxf((float)hist[seg], 1.f);
  ei2[pos] = make_int2(src[e] * NR + r, sc.i);
}

// ---------- W split+transpose: Wt[c][k], c in [0,1152), k in [0,128) ----------
__global__ __launch_bounds__(128) void k_wsplit(const float* __restrict__ W1, const float* __restrict__ Wr1,
                                                ushort* __restrict__ WtH, ushort* __restrict__ WtL) {
  int c = blockIdx.x;          // 0..1151
  int k = threadIdx.x;         // 0..127
  float v;
  if (c < 1024) {
    int r = c >> 7, col = c & 127;
    v = W1[((size_t)r * 128 + k) * 128 + col];
  } else {
    v = Wr1[(size_t)k * 128 + (c - 1024)];
  }
  ushort hi = f2bf(v);
  ushort lo = f2bf(v - bf2f(hi));
  WtH[(size_t)c * 128 + k] = hi;
  WtL[(size_t)c * 128 + k] = lo;
}

// ---------- dense GEMM: Y[N,1152] = bf16(x[N,128]) @ Wt^T, bf16 out (r18 exact) ----------
__global__ __launch_bounds__(256) void k_gemm_dense(
    const float* __restrict__ x,
    const ushort* __restrict__ WtH, const ushort* __restrict__ WtL,
    ushort* __restrict__ Y, int N) {
  int tid = threadIdx.x;
  int w = tid >> 6, lane = tid & 63;
  int n0 = blockIdx.x * 64;
  int wbase = w * 288;

  int frow = lane & 15;
  int fk8 = (lane >> 4) * 8;
  int q4 = (lane >> 4) * 4;

  int anode[4];
  bool nodeok[4];
  size_t ybase[4];
  #pragma unroll
  for (int nf = 0; nf < 4; nf++) {
    int n = n0 + nf * 16 + frow;
    nodeok[nf] = (n < N);
    anode[nf] = nodeok[nf] ? n : (N - 1);
    ybase[nf] = (size_t)anode[nf] * 1152 + q4;
  }

  uint4 xbr[4][4];
  #pragma unroll
  for (int nf = 0; nf < 4; nf++) {
    #pragma unroll
    for (int kc = 0; kc < 4; kc++) {
      const float4* xp = (const float4*)(x + (size_t)anode[nf] * 128 + kc * 32 + fk8);
      float4 v0 = xp[0], v1 = xp[1];
      uint4 o;
      o.x = pk2(v0.x, v0.y);
      o.y = pk2(v0.z, v0.w);
      o.z = pk2(v1.x, v1.y);
      o.w = pk2(v1.z, v1.w);
      xbr[nf][kc] = o;
    }
  }

  f32x4 acc[2][4];
  uint4 pw0[2][2], pw1[2][2];

  #define LOADW(P, CB, KC)                                                     \
    {                                                                          \
      _Pragma("unroll")                                                        \
      for (int cf = 0; cf < 2; cf++) {                                         \
        int c_ = (CB) + cf * 16 + frow;                                        \
        P[cf][0] = *(const uint4*)(WtH + (size_t)c_ * 128 + (KC) * 32 + fk8);  \
        P[cf][1] = *(const uint4*)(WtL + (size_t)c_ * 128 + (KC) * 32 + fk8);  \
      }                                                                        \
    }
  #define KSTEP(KC, PWU)                                                       \
    {                                                                          \
      _Pragma("unroll")                                                        \
      for (int cf = 0; cf < 2; cf++) {                                         \
        U128 wh_, wl_;                                                         \
        wh_.u = PWU[cf][0];                                                    \
        wl_.u = PWU[cf][1];                                                    \
        _Pragma("unroll")                                                      \
        for (int nf = 0; nf < 4; nf++) {                                       \
          U128 xv_;                                                            \
          xv_.u = xbr[nf][KC];                                                 \
          acc[cf][nf] = __builtin_amdgcn_mfma_f32_16x16x32_bf16(wh_.s, xv_.s, acc[cf][nf], 0, 0, 0); \
          acc[cf][nf] = __builtin_amdgcn_mfma_f32_16x16x32_bf16(wl_.s, xv_.s, acc[cf][nf], 0, 0, 0); \
        }                                                                      \
      }                                                                        \
    }
  #define CHUNK(CB, NCB, ISLAST)                                               \
    {                                                                          \
      _Pragma("unroll")                                                        \
      for (int cf = 0; cf < 2; cf++)                                           \
        _Pragma("unroll")                                                      \
        for (int nf = 0; nf < 4; nf++) acc[cf][nf] = (f32x4){0.f, 0.f, 0.f, 0.f}; \
      LOADW(pw1, CB, 1);                                                       \
      KSTEP(0, pw0);                                                           \
      LOADW(pw0, CB, 2);                                                       \
      KSTEP(1, pw1);                                                           \
      LOADW(pw1, CB, 3);                                                       \
      KSTEP(2, pw0);                                                           \
      if (!(ISLAST)) { LOADW(pw0, NCB, 0); }                                   \
      KSTEP(3, pw1);                                                           \
      _Pragma("unroll")                                                        \
      for (int cf = 0; cf < 2; cf++)                                           \
        _Pragma("unroll")                                                      \
        for (int nf = 0; nf < 4; nf++) {                                       \
          if (nodeok[nf]) {                                                    \
            ushort4 o_;                                                        \
            o_.x = f2bf(acc[cf][nf][0]);                                       \
            o_.y = f2bf(acc[cf][nf][1]);                                       \
            o_.z = f2bf(acc[cf][nf][2]);                                       \
            o_.w = f2bf(acc[cf][nf][3]);                                       \
            *(ushort4*)(Y + ybase[nf] + (CB) + cf * 16) = o_;                  \
          }                                                                    \
        }                                                                      \
    }

  LOADW(pw0, wbase, 0);

  CHUNK(wbase + 0,   wbase + 32,  0)
  CHUNK(wbase + 32,  wbase + 64,  0)
  CHUNK(wbase + 64,  wbase + 96,  0)
  CHUNK(wbase + 96,  wbase + 128, 0)
  CHUNK(wbase + 128, wbase + 160, 0)
  CHUNK(wbase + 160, wbase + 192, 0)
  CHUNK(wbase + 192, wbase + 224, 0)
  CHUNK(wbase + 224, wbase + 256, 0)
  CHUNK(wbase + 256, 0,           1)

  #undef LOADW
  #undef KSTEP
  #undef CHUNK
}

// ---------- fused flat h-gather + layer-2 transform (8-deep pipeline) ----------
__global__ __launch_bounds__(256) void k_hgather(const int* __restrict__ offs, const int* __restrict__ hist,
                                                 const int2* __restrict__ ei2, const ushort* __restrict__ Y,
                                                 const float* __restrict__ b1,
                                                 const float* __restrict__ W2, const float* __restrict__ Wr2,
                                                 float* __restrict__ t, int N) {
  __shared__ float Wt[18 * 128];
  int tid = threadIdx.x;
  for (int i = tid; i < 2304; i += 256) {
    float v; int oc, d;
    if (i < 2048) { int r = i >> 8, rem = i & 255; d = rem >> 1; int c = rem & 1; oc = r * 2 + c; v = W2[i]; }
    else { int i2 = i - 2048; d = i2 >> 1; int c = i2 & 1; oc = 16 + c; v = Wr2[i2]; }
    Wt[oc * 128 + d] = v;
  }
  __syncthreads();

  int node = blockIdx.x * 4 + (tid >> 6);
  int lane = tid & 63;
  if (node >= N) return;
  int c0 = lane * 2;
  int seg0 = node * NR;
  int st = offs[seg0] - hist[seg0];
  int en = offs[seg0 + 7];

  uint vroot = *(const uint*)(Y + (size_t)node * 1152 + 1024 + c0);
  float2 bb = *(const float2*)(b1 + c0);
  float ax = bf2f((ushort)(vroot & 0xffff)) + bb.x;
  float ay = bf2f((ushort)(vroot >> 16)) + bb.y;

  int i = st;
  for (; i + 8 <= en; i += 8) {
    int2 e0 = ei2[i + 0];
    int2 e1 = ei2[i + 1];
    int2 e2 = ei2[i + 2];
    int2 e3 = ei2[i + 3];
    int2 e4 = ei2[i + 4];
    int2 e5 = ei2[i + 5];
    int2 e6 = ei2[i + 6];
    int2 e7 = ei2[i + 7];
    uint v0 = *(const uint*)(Y + (((uint)(e0.x + (e0.x >> 3)) << 7) + c0));
    uint v1 = *(const uint*)(Y + (((uint)(e1.x + (e1.x >> 3)) << 7) + c0));
    uint v2 = *(const uint*)(Y + (((uint)(e2.x + (e2.x >> 3)) << 7) + c0));
    uint v3 = *(const uint*)(Y + (((uint)(e3.x + (e3.x >> 3)) << 7) + c0));
    uint v4 = *(const uint*)(Y + (((uint)(e4.x + (e4.x >> 3)) << 7) + c0));
    uint v5 = *(const uint*)(Y + (((uint)(e5.x + (e5.x >> 3)) << 7) + c0));
    uint v6 = *(const uint*)(Y + (((uint)(e6.x + (e6.x >> 3)) << 7) + c0));
    uint v7 = *(const uint*)(Y + (((uint)(e7.x + (e7.x >> 3)) << 7) + c0));
    FU s0, s1, s2, s3, s4, s5, s6, s7;
    s0.i = e0.y; s1.i = e1.y; s2.i = e2.y; s3.i = e3.y;
    s4.i = e4.y; s5.i = e5.y; s6.i = e6.y; s7.i = e7.y;
    ax += bf2f((ushort)(v0 & 0xffff)) * s0.f + bf2f((ushort)(v1 & 0xffff)) * s1.f +
          bf2f((ushort)(v2 & 0xffff)) * s2.f + bf2f((ushort)(v3 & 0xffff)) * s3.f +
          bf2f((ushort)(v4 & 0xffff)) * s4.f + bf2f((ushort)(v5 & 0xffff)) * s5.f +
          bf2f((ushort)(v6 & 0xffff)) * s6.f + bf2f((ushort)(v7 & 0xffff)) * s7.f;
    ay += bf2f((ushort)(v0 >> 16)) * s0.f + bf2f((ushort)(v1 >> 16)) * s1.f +
          bf2f((ushort)(v2 >> 16)) * s2.f + bf2f((ushort)(v3 >> 16)) * s3.f +
          bf2f((ushort)(v4 >> 16)) * s4.f + bf2f((ushort)(v5 >> 16)) * s5.f +
          bf2f((ushort)(v6 >> 16)) * s6.f + bf2f((ushort)(v7 >> 16)) * s7.f;
  }
  for (; i + 4 <= en; i += 4) {
    int2 e0 = ei2[i + 0];
    int2 e1 = ei2[i + 1];
    int2 e2 = ei2[i + 2];
    int2 e3 = ei2[i + 3];
    uint v0 = *(const uint*)(Y + (((uint)(e0.x + (e0.x >> 3)) << 7) + c0));
    uint v1 = *(const uint*)(Y + (((uint)(e1.x + (e1.x >> 3)) << 7) + c0));
    uint v2 = *(const uint*)(Y + (((uint)(e2.x + (e2.x >> 3)) << 7) + c0));
    uint v3 = *(const uint*)(Y + (((uint)(e3.x + (e3.x >> 3)) << 7) + c0));
    FU s0, s1, s2, s3;
    s0.i = e0.y; s1.i = e1.y; s2.i = e2.y; s3.i = e3.y;
    ax += bf2f((ushort)(v0 & 0xffff)) * s0.f + bf2f((ushort)(v1 & 0xffff)) * s1.f +
          bf2f((ushort)(v2 & 0xffff)) * s2.f + bf2f((ushort)(v3 & 0xffff)) * s3.f;
    ay += bf2f((ushort)(v0 >> 16)) * s0.f + bf2f((ushort)(v1 >> 16)) * s1.f +
          bf2f((ushort)(v2 >> 16)) * s2.f + bf2f((ushort)(v3 >> 16)) * s3.f;
  }
  for (; i < en; i++) {
    int2 e = ei2[i];
    uint v = *(const uint*)(Y + (((uint)(e.x + (e.x >> 3)) << 7) + c0));
    FU sc; sc.i = e.y;
    ax += bf2f((ushort)(v & 0xffff)) * sc.f;
    ay += bf2f((ushort)(v >> 16)) * sc.f;
  }

  float hx = fmaxf(ax, 0.f);
  float hy = fmaxf(ay, 0.f);

  #pragma unroll
  for (int oc = 0; oc < 18; oc++) {
    float2 wv = *(const float2*)(Wt + oc * 128 + c0);
    float p = hx * wv.x + hy * wv.y;
    p += __shfl_xor(p, 32); p += __shfl_xor(p, 16); p += __shfl_xor(p, 8);
    p += __shfl_xor(p, 4);  p += __shfl_xor(p, 2);  p += __shfl_xor(p, 1);
    if (lane == 0) t[(size_t)node * 18 + oc] = p;
  }
}

// ---------- output: 8 lanes per node (lane = relation), scale pre-folded ----------
__global__ __launch_bounds__(256) void k_out2(const int* __restrict__ offs, const int* __restrict__ hist,
                                              const int2* __restrict__ ei2, const float* __restrict__ t,
                                              const float* __restrict__ b2, float* __restrict__ out, int N) {
  int tid = threadIdx.x;
  int node = blockIdx.x * 32 + (tid >> 3);
  int r = tid & 7;
  if (node >= N) return;
  int seg = node * NR + r;
  int en = offs[seg];
  int cc = hist[seg];
  float s0 = 0.f, s1 = 0.f;
  for (int i = en - cc; i < en; i++) {
    int2 e = ei2[i];
    int src = e.x >> 3;
    FU sc; sc.i = e.y;
    float2 tv = *(const float2*)(t + (size_t)src * 18 + r * 2);
    s0 += tv.x * sc.f;
    s1 += tv.y * sc.f;
  }
  s0 += __shfl_xor(s0, 1); s1 += __shfl_xor(s1, 1);
  s0 += __shfl_xor(s0, 2); s1 += __shfl_xor(s1, 2);
  s0 += __shfl_xor(s0, 4); s1 += __shfl_xor(s1, 4);
  if (r == 0) {
    out[(size_t)node * 2 + 0] = s0 + t[(size_t)node * 18 + 16] + b2[0];
    out[(size_t)node * 2 + 1] = s1 + t[(size_t)node * 18 + 17] + b2[1];
  }
}

extern "C" void kernel_launch(void* const* d_in, const int* in_sizes, int n_in,
                              void* d_out, int out_size, void* d_ws, size_t ws_size,
                              hipStream_t stream) {
  const float* x   = (const float*)d_in[0];
  const int*   ei  = (const int*)d_in[1];
  const int*   et  = (const int*)d_in[2];
  const float* W1  = (const float*)d_in[3];
  const float* Wr1 = (const float*)d_in[4];
  const float* b1  = (const float*)d_in[5];
  const float* W2  = (const float*)d_in[6];
  const float* Wr2 = (const float*)d_in[7];
  const float* b2  = (const float*)d_in[8];
  float* out = (float*)d_out;

  int E = in_sizes[1] / 2;
  int N = in_sizes[0] / DH;
  int S = N * NR;
  const int* src = ei;
  const int* dst = ei + E;

  // ws layout: ints | ei2 (int2, E) | WtH WtL | Y (bf16, N*1152) | t
  int* hist       = (int*)d_ws;                  // S
  int* offs       = hist + S;                    // S
  int* blksum     = offs + S;                    // 1024
  int* blkoff     = blksum + 1024;               // 1024
  int2* ei2       = (int2*)(blkoff + 1024);      // E int2 (8B-aligned)
  size_t int_elems = (size_t)S * 2 + 2048 + (size_t)E * 2;
  int_elems = (int_elems + 3) & ~(size_t)3;      // 16B align
  ushort* WtH = (ushort*)(hist + int_elems);     // 1152*128
  ushort* WtL = WtH + 1152 * 128;                // 1152*128
  ushort* Y   = WtL + 1152 * 128;                // N*1152
  size_t ush_elems = 2 * 1152 * 128 + (size_t)N * 1152;
  ush_elems = (ush_elems + 1) & ~(size_t)1;      // float align
  float* t = (float*)(WtH + ush_elems);          // N*18

  hipMemsetAsync(hist, 0, sizeof(int) * (size_t)S, stream);

  k_hist<<<(E + 255) / 256, 256, 0, stream>>>(dst, et, hist, E);

  int NB = (S + 1023) / 1024;
  k_scan_local<<<NB, 256, 0, stream>>>(hist, offs, blksum, S);
  k_scan_blk<<<1, 512, 0, stream>>>(blksum, blkoff, NB);
  k_scan_add<<<NB, 256, 0, stream>>>(offs, blkoff, S);

  k_scatter_idx<<<(E + 255) / 256, 256, 0, stream>>>(src, dst, et, hist, offs, ei2, E);

  k_wsplit<<<1152, 128, 0, stream>>>(W1, Wr1, WtH, WtL);

  k_gemm_dense<<<(N + 63) / 64, 256, 0, stream>>>(x, WtH, WtL, Y, N);

  k_hgather<<<(N + 3) / 4, 256, 0, stream>>>(offs, hist, ei2, Y, b1, W2, Wr2, t, N);

  k_out2<<<(N + 31) / 32, 256, 0, stream>>>(offs, hist, ei2, t, b2, out, N);
}

// Round 24
// 255.310 us; speedup vs baseline: 1.1888x; 1.1001x over previous
//
#include <hip/hip_runtime.h>
#include <hip/hip_bf16.h>

// RGCN 2-layer forward. Transform-then-aggregate on BOTH layers.
// L1: Y[n,0:1152] = bf16(x[n]) @ [W_r0..W_r7 | Wroot]  (dense bf16 MFMA GEMM,
//     operand-swapped, r18 geometry, frozen at ~102us plateau).
// Sort: counting sort -> ei2[pos] = {src*8+rel, bits(1/cnt)} (mean folded/edge).
// hgather (this round): HALF-WAVE per node (8 nodes/block, 32 lanes x 4 cols,
//     uint2 loads), 8-deep pipeline -> 16 Y-loads in flight per wave;
//     fused layer-2 transform -> t[n,0:18].
// out2: 8 lanes/node (lane=relation), scale pre-folded.

#define NR 8
#define DH 128

typedef short short8 __attribute__((ext_vector_type(8)));
typedef float f32x4 __attribute__((ext_vector_type(4)));

__device__ inline ushort f2bf(float v) {
  __hip_bfloat16 b = __float2bfloat16(v);
  return *reinterpret_cast<ushort*>(&b);
}
__device__ inline float bf2f(ushort u) {
  __hip_bfloat16 b;
  *reinterpret_cast<ushort*>(&b) = u;
  return __bfloat162float(b);
}
__device__ inline uint pk2(float lo, float hi) {
  return (uint)f2bf(lo) | ((uint)f2bf(hi) << 16);
}
union U128 { uint4 u; short8 s; };
union FU { float f; int i; };

// ---------- counting sort ----------
__global__ __launch_bounds__(256) void k_hist(const int* __restrict__ dst, const int* __restrict__ et,
                                              int* __restrict__ hist, int E) {
  int e = blockIdx.x * 256 + threadIdx.x;
  if (e < E) atomicAdd(&hist[dst[e] * NR + et[e]], 1);
}

__global__ __launch_bounds__(256) void k_scan_local(const int* __restrict__ hist, int* __restrict__ offs,
                                                    int* __restrict__ blksum, int S) {
  __shared__ int tsum[256];
  int tid = threadIdx.x;
  int base = blockIdx.x * 1024 + tid * 4;
  int v[4], tot = 0;
  #pragma unroll
  for (int i = 0; i < 4; i++) { v[i] = (base + i < S) ? hist[base + i] : 0; tot += v[i]; }
  tsum[tid] = tot;
  __syncthreads();
  for (int off = 1; off < 256; off <<= 1) {
    int val = tsum[tid];
    int add = (tid >= off) ? tsum[tid - off] : 0;
    __syncthreads();
    tsum[tid] = val + add;
    __syncthreads();
  }
  int run = tsum[tid] - tot;
  #pragma unroll
  for (int i = 0; i < 4; i++) {
    if (base + i < S) offs[base + i] = run;
    run += v[i];
  }
  if (tid == 255) blksum[blockIdx.x] = tsum[255];
}

__global__ __launch_bounds__(512) void k_scan_blk(const int* __restrict__ blksum, int* __restrict__ blkoff, int NB) {
  __shared__ int s[512];
  int tid = threadIdx.x;
  int v = (tid < NB) ? blksum[tid] : 0;
  s[tid] = v;
  __syncthreads();
  for (int off = 1; off < 512; off <<= 1) {
    int val = s[tid];
    int add = (tid >= off) ? s[tid - off] : 0;
    __syncthreads();
    s[tid] = val + add;
    __syncthreads();
  }
  if (tid < NB) blkoff[tid] = s[tid] - v;
}

__global__ __launch_bounds__(256) void k_scan_add(int* __restrict__ offs, const int* __restrict__ blkoff, int S) {
  int tid = threadIdx.x;
  int base = blockIdx.x * 1024 + tid * 4;
  int add = blkoff[blockIdx.x];
  #pragma unroll
  for (int i = 0; i < 4; i++)
    if (base + i < S) offs[base + i] += add;
}

// scatter: ei2[pos] = {src*8+rel, bits(1/cnt)}; offs[seg] becomes segment END
__global__ __launch_bounds__(256) void k_scatter_idx(const int* __restrict__ src, const int* __restrict__ dst,
                                                     const int* __restrict__ et, const int* __restrict__ hist,
                                                     int* __restrict__ offs, int2* __restrict__ ei2, int E) {
  int e = blockIdx.x * 256 + threadIdx.x;
  if (e >= E) return;
  int r = et[e];
  int seg = dst[e] * NR + r;
  int pos = atomicAdd(&offs[seg], 1);
  FU sc;
  sc.f = 1.f / fmaxf((float)hist[seg], 1.f);
  ei2[pos] = make_int2(src[e] * NR + r, sc.i);
}

// ---------- W split+transpose: Wt[c][k], c in [0,1152), k in [0,128) ----------
__global__ __launch_bounds__(128) void k_wsplit(const float* __restrict__ W1, const float* __restrict__ Wr1,
                                                ushort* __restrict__ WtH, ushort* __restrict__ WtL) {
  int c = blockIdx.x;          // 0..1151
  int k = threadIdx.x;         // 0..127
  float v;
  if (c < 1024) {
    int r = c >> 7, col = c & 127;
    v = W1[((size_t)r * 128 + k) * 128 + col];
  } else {
    v = Wr1[(size_t)k * 128 + (c - 1024)];
  }
  ushort hi = f2bf(v);
  ushort lo = f2bf(v - bf2f(hi));
  WtH[(size_t)c * 128 + k] = hi;
  WtL[(size_t)c * 128 + k] = lo;
}

// ---------- dense GEMM: Y[N,1152] = bf16(x[N,128]) @ Wt^T, bf16 out (r18 exact) ----------
__global__ __launch_bounds__(256) void k_gemm_dense(
    const float* __restrict__ x,
    const ushort* __restrict__ WtH, const ushort* __restrict__ WtL,
    ushort* __restrict__ Y, int N) {
  int tid = threadIdx.x;
  int w = tid >> 6, lane = tid & 63;
  int n0 = blockIdx.x * 64;
  int wbase = w * 288;

  int frow = lane & 15;
  int fk8 = (lane >> 4) * 8;
  int q4 = (lane >> 4) * 4;

  int anode[4];
  bool nodeok[4];
  size_t ybase[4];
  #pragma unroll
  for (int nf = 0; nf < 4; nf++) {
    int n = n0 + nf * 16 + frow;
    nodeok[nf] = (n < N);
    anode[nf] = nodeok[nf] ? n : (N - 1);
    ybase[nf] = (size_t)anode[nf] * 1152 + q4;
  }

  uint4 xbr[4][4];
  #pragma unroll
  for (int nf = 0; nf < 4; nf++) {
    #pragma unroll
    for (int kc = 0; kc < 4; kc++) {
      const float4* xp = (const float4*)(x + (size_t)anode[nf] * 128 + kc * 32 + fk8);
      float4 v0 = xp[0], v1 = xp[1];
      uint4 o;
      o.x = pk2(v0.x, v0.y);
      o.y = pk2(v0.z, v0.w);
      o.z = pk2(v1.x, v1.y);
      o.w = pk2(v1.z, v1.w);
      xbr[nf][kc] = o;
    }
  }

  f32x4 acc[2][4];
  uint4 pw0[2][2], pw1[2][2];

  #define LOADW(P, CB, KC)                                                     \
    {                                                                          \
      _Pragma("unroll")                                                        \
      for (int cf = 0; cf < 2; cf++) {                                         \
        int c_ = (CB) + cf * 16 + frow;                                        \
        P[cf][0] = *(const uint4*)(WtH + (size_t)c_ * 128 + (KC) * 32 + fk8);  \
        P[cf][1] = *(const uint4*)(WtL + (size_t)c_ * 128 + (KC) * 32 + fk8);  \
      }                                                                        \
    }
  #define KSTEP(KC, PWU)                                                       \
    {                                                                          \
      _Pragma("unroll")                                                        \
      for (int cf = 0; cf < 2; cf++) {                                         \
        U128 wh_, wl_;                                                         \
        wh_.u = PWU[cf][0];                                                    \
        wl_.u = PWU[cf][1];                                                    \
        _Pragma("unroll")                                                      \
        for (int nf = 0; nf < 4; nf++) {                                       \
          U128 xv_;                                                            \
          xv_.u = xbr[nf][KC];                                                 \
          acc[cf][nf] = __builtin_amdgcn_mfma_f32_16x16x32_bf16(wh_.s, xv_.s, acc[cf][nf], 0, 0, 0); \
          acc[cf][nf] = __builtin_amdgcn_mfma_f32_16x16x32_bf16(wl_.s, xv_.s, acc[cf][nf], 0, 0, 0); \
        }                                                                      \
      }                                                                        \
    }
  #define CHUNK(CB, NCB, ISLAST)                                               \
    {                                                                          \
      _Pragma("unroll")                                                        \
      for (int cf = 0; cf < 2; cf++)                                           \
        _Pragma("unroll")                                                      \
        for (int nf = 0; nf < 4; nf++) acc[cf][nf] = (f32x4){0.f, 0.f, 0.f, 0.f}; \
      LOADW(pw1, CB, 1);                                                       \
      KSTEP(0, pw0);                                                           \
      LOADW(pw0, CB, 2);                                                       \
      KSTEP(1, pw1);                                                           \
      LOADW(pw1, CB, 3);                                                       \
      KSTEP(2, pw0);                                                           \
      if (!(ISLAST)) { LOADW(pw0, NCB, 0); }                                   \
      KSTEP(3, pw1);                                                           \
      _Pragma("unroll")                                                        \
      for (int cf = 0; cf < 2; cf++)                                           \
        _Pragma("unroll")                                                      \
        for (int nf = 0; nf < 4; nf++) {                                       \
          if (nodeok[nf]) {                                                    \
            ushort4 o_;                                                        \
            o_.x = f2bf(acc[cf][nf][0]);                                       \
            o_.y = f2bf(acc[cf][nf][1]);                                       \
            o_.z = f2bf(acc[cf][nf][2]);                                       \
            o_.w = f2bf(acc[cf][nf][3]);                                       \
            *(ushort4*)(Y + ybase[nf] + (CB) + cf * 16) = o_;                  \
          }                                                                    \
        }                                                                      \
    }

  LOADW(pw0, wbase, 0);

  CHUNK(wbase + 0,   wbase + 32,  0)
  CHUNK(wbase + 32,  wbase + 64,  0)
  CHUNK(wbase + 64,  wbase + 96,  0)
  CHUNK(wbase + 96,  wbase + 128, 0)
  CHUNK(wbase + 128, wbase + 160, 0)
  CHUNK(wbase + 160, wbase + 192, 0)
  CHUNK(wbase + 192, wbase + 224, 0)
  CHUNK(wbase + 224, wbase + 256, 0)
  CHUNK(wbase + 256, 0,           1)

  #undef LOADW
  #undef KSTEP
  #undef CHUNK
}

// ---------- fused h-gather + layer-2 transform: half-wave per node ----------
// 256 thr = 8 nodes/block; hl = lane&31 covers cols [hl*4, hl*4+4) (uint2).
// Flat edge loop 8-deep => 16 Y-loads in flight per wave (2 nodes).
__global__ __launch_bounds__(256) void k_hgather(const int* __restrict__ offs, const int* __restrict__ hist,
                                                 const int2* __restrict__ ei2, const ushort* __restrict__ Y,
                                                 const float* __restrict__ b1,
                                                 const float* __restrict__ W2, const float* __restrict__ Wr2,
                                                 float* __restrict__ t, int N) {
  __shared__ float Wt[18 * 128];
  int tid = threadIdx.x;
  for (int i = tid; i < 2304; i += 256) {
    float v; int oc, d;
    if (i < 2048) { int r = i >> 8, rem = i & 255; d = rem >> 1; int c = rem & 1; oc = r * 2 + c; v = W2[i]; }
    else { int i2 = i - 2048; d = i2 >> 1; int c = i2 & 1; oc = 16 + c; v = Wr2[i2]; }
    Wt[oc * 128 + d] = v;
  }
  __syncthreads();

  int node = blockIdx.x * 8 + (tid >> 5);
  int hl = tid & 31;
  if (node >= N) return;
  int c0 = hl * 4;
  int seg0 = node * NR;
  int st = offs[seg0] - hist[seg0];
  int en = offs[seg0 + 7];

  uint2 vr = *(const uint2*)(Y + (size_t)node * 1152 + 1024 + c0);
  float4 bb = *(const float4*)(b1 + c0);
  float a0 = bf2f((ushort)(vr.x & 0xffff)) + bb.x;
  float a1 = bf2f((ushort)(vr.x >> 16)) + bb.y;
  float a2 = bf2f((ushort)(vr.y & 0xffff)) + bb.z;
  float a3 = bf2f((ushort)(vr.y >> 16)) + bb.w;

  int i = st;
  for (; i + 8 <= en; i += 8) {
    int2 e0 = ei2[i + 0];
    int2 e1 = ei2[i + 1];
    int2 e2 = ei2[i + 2];
    int2 e3 = ei2[i + 3];
    int2 e4 = ei2[i + 4];
    int2 e5 = ei2[i + 5];
    int2 e6 = ei2[i + 6];
    int2 e7 = ei2[i + 7];
    uint2 v0 = *(const uint2*)(Y + (((uint)(e0.x + (e0.x >> 3)) << 7) + c0));
    uint2 v1 = *(const uint2*)(Y + (((uint)(e1.x + (e1.x >> 3)) << 7) + c0));
    uint2 v2 = *(const uint2*)(Y + (((uint)(e2.x + (e2.x >> 3)) << 7) + c0));
    uint2 v3 = *(const uint2*)(Y + (((uint)(e3.x + (e3.x >> 3)) << 7) + c0));
    uint2 v4 = *(const uint2*)(Y + (((uint)(e4.x + (e4.x >> 3)) << 7) + c0));
    uint2 v5 = *(const uint2*)(Y + (((uint)(e5.x + (e5.x >> 3)) << 7) + c0));
    uint2 v6 = *(const uint2*)(Y + (((uint)(e6.x + (e6.x >> 3)) << 7) + c0));
    uint2 v7 = *(const uint2*)(Y + (((uint)(e7.x + (e7.x >> 3)) << 7) + c0));
    FU s0, s1, s2, s3, s4, s5, s6, s7;
    s0.i = e0.y; s1.i = e1.y; s2.i = e2.y; s3.i = e3.y;
    s4.i = e4.y; s5.i = e5.y; s6.i = e6.y; s7.i = e7.y;
    a0 += bf2f((ushort)(v0.x & 0xffff)) * s0.f + bf2f((ushort)(v1.x & 0xffff)) * s1.f +
          bf2f((ushort)(v2.x & 0xffff)) * s2.f + bf2f((ushort)(v3.x & 0xffff)) * s3.f +
          bf2f((ushort)(v4.x & 0xffff)) * s4.f + bf2f((ushort)(v5.x & 0xffff)) * s5.f +
          bf2f((ushort)(v6.x & 0xffff)) * s6.f + bf2f((ushort)(v7.x & 0xffff)) * s7.f;
    a1 += bf2f((ushort)(v0.x >> 16)) * s0.f + bf2f((ushort)(v1.x >> 16)) * s1.f +
          bf2f((ushort)(v2.x >> 16)) * s2.f + bf2f((ushort)(v3.x >> 16)) * s3.f +
          bf2f((ushort)(v4.x >> 16)) * s4.f + bf2f((ushort)(v5.x >> 16)) * s5.f +
          bf2f((ushort)(v6.x >> 16)) * s6.f + bf2f((ushort)(v7.x >> 16)) * s7.f;
    a2 += bf2f((ushort)(v0.y & 0xffff)) * s0.f + bf2f((ushort)(v1.y & 0xffff)) * s1.f +
          bf2f((ushort)(v2.y & 0xffff)) * s2.f + bf2f((ushort)(v3.y & 0xffff)) * s3.f +
          bf2f((ushort)(v4.y & 0xffff)) * s4.f + bf2f((ushort)(v5.y & 0xffff)) * s5.f +
          bf2f((ushort)(v6.y & 0xffff)) * s6.f + bf2f((ushort)(v7.y & 0xffff)) * s7.f;
    a3 += bf2f((ushort)(v0.y >> 16)) * s0.f + bf2f((ushort)(v1.y >> 16)) * s1.f +
          bf2f((ushort)(v2.y >> 16)) * s2.f + bf2f((ushort)(v3.y >> 16)) * s3.f +
          bf2f((ushort)(v4.y >> 16)) * s4.f + bf2f((ushort)(v5.y >> 16)) * s5.f +
          bf2f((ushort)(v6.y >> 16)) * s6.f + bf2f((ushort)(v7.y >> 16)) * s7.f;
  }
  for (; i + 4 <= en; i += 4) {
    int2 e0 = ei2[i + 0];
    int2 e1 = ei2[i + 1];
    int2 e2 = ei2[i + 2];
    int2 e3 = ei2[i + 3];
    uint2 v0 = *(const uint2*)(Y + (((uint)(e0.x + (e0.x >> 3)) << 7) + c0));
    uint2 v1 = *(const uint2*)(Y + (((uint)(e1.x + (e1.x >> 3)) << 7) + c0));
    uint2 v2 = *(const uint2*)(Y + (((uint)(e2.x + (e2.x >> 3)) << 7) + c0));
    uint2 v3 = *(const uint2*)(Y + (((uint)(e3.x + (e3.x >> 3)) << 7) + c0));
    FU s0, s1, s2, s3;
    s0.i = e0.y; s1.i = e1.y; s2.i = e2.y; s3.i = e3.y;
    a0 += bf2f((ushort)(v0.x & 0xffff)) * s0.f + bf2f((ushort)(v1.x & 0xffff)) * s1.f +
          bf2f((ushort)(v2.x & 0xffff)) * s2.f + bf2f((ushort)(v3.x & 0xffff)) * s3.f;
    a1 += bf2f((ushort)(v0.x >> 16)) * s0.f + bf2f((ushort)(v1.x >> 16)) * s1.f +
          bf2f((ushort)(v2.x >> 16)) * s2.f + bf2f((ushort)(v3.x >> 16)) * s3.f;
    a2 += bf2f((ushort)(v0.y & 0xffff)) * s0.f + bf2f((ushort)(v1.y & 0xffff)) * s1.f +
          bf2f((ushort)(v2.y & 0xffff)) * s2.f + bf2f((ushort)(v3.y & 0xffff)) * s3.f;
    a3 += bf2f((ushort)(v0.y >> 16)) * s0.f + bf2f((ushort)(v1.y >> 16)) * s1.f +
          bf2f((ushort)(v2.y >> 16)) * s2.f + bf2f((ushort)(v3.y >> 16)) * s3.f;
  }
  for (; i < en; i++) {
    int2 e = ei2[i];
    uint2 v = *(const uint2*)(Y + (((uint)(e.x + (e.x >> 3)) << 7) + c0));
    FU sc; sc.i = e.y;
    a0 += bf2f((ushort)(v.x & 0xffff)) * sc.f;
    a1 += bf2f((ushort)(v.x >> 16)) * sc.f;
    a2 += bf2f((ushort)(v.y & 0xffff)) * sc.f;
    a3 += bf2f((ushort)(v.y >> 16)) * sc.f;
  }

  float h0 = fmaxf(a0, 0.f);
  float h1 = fmaxf(a1, 0.f);
  float h2 = fmaxf(a2, 0.f);
  float h3 = fmaxf(a3, 0.f);

  #pragma unroll
  for (int oc = 0; oc < 18; oc++) {
    float4 wv = *(const float4*)(Wt + oc * 128 + c0);
    float p = h0 * wv.x + h1 * wv.y + h2 * wv.z + h3 * wv.w;
    p += __shfl_xor(p, 16); p += __shfl_xor(p, 8);
    p += __shfl_xor(p, 4);  p += __shfl_xor(p, 2);  p += __shfl_xor(p, 1);
    if (hl == 0) t[(size_t)node * 18 + oc] = p;
  }
}

// ---------- output: 8 lanes per node (lane = relation), scale pre-folded ----------
__global__ __launch_bounds__(256) void k_out2(const int* __restrict__ offs, const int* __restrict__ hist,
                                              const int2* __restrict__ ei2, const float* __restrict__ t,
                                              const float* __restrict__ b2, float* __restrict__ out, int N) {
  int tid = threadIdx.x;
  int node = blockIdx.x * 32 + (tid >> 3);
  int r = tid & 7;
  if (node >= N) return;
  int seg = node * NR + r;
  int en = offs[seg];
  int cc = hist[seg];
  float s0 = 0.f, s1 = 0.f;
  for (int i = en - cc; i < en; i++) {
    int2 e = ei2[i];
    int src = e.x >> 3;
    FU sc; sc.i = e.y;
    float2 tv = *(const float2*)(t + (size_t)src * 18 + r * 2);
    s0 += tv.x * sc.f;
    s1 += tv.y * sc.f;
  }
  s0 += __shfl_xor(s0, 1); s1 += __shfl_xor(s1, 1);
  s0 += __shfl_xor(s0, 2); s1 += __shfl_xor(s1, 2);
  s0 += __shfl_xor(s0, 4); s1 += __shfl_xor(s1, 4);
  if (r == 0) {
    out[(size_t)node * 2 + 0] = s0 + t[(size_t)node * 18 + 16] + b2[0];
    out[(size_t)node * 2 + 1] = s1 + t[(size_t)node * 18 + 17] + b2[1];
  }
}

extern "C" void kernel_launch(void* const* d_in, const int* in_sizes, int n_in,
                              void* d_out, int out_size, void* d_ws, size_t ws_size,
                              hipStream_t stream) {
  const float* x   = (const float*)d_in[0];
  const int*   ei  = (const int*)d_in[1];
  const int*   et  = (const int*)d_in[2];
  const float* W1  = (const float*)d_in[3];
  const float* Wr1 = (const float*)d_in[4];
  const float* b1  = (const float*)d_in[5];
  const float* W2  = (const float*)d_in[6];
  const float* Wr2 = (const float*)d_in[7];
  const float* b2  = (const float*)d_in[8];
  float* out = (float*)d_out;

  int E = in_sizes[1] / 2;
  int N = in_sizes[0] / DH;
  int S = N * NR;
  const int* src = ei;
  const int* dst = ei + E;

  // ws layout: ints | ei2 (int2, E) | WtH WtL | Y (bf16, N*1152) | t
  int* hist       = (int*)d_ws;                  // S
  int* offs       = hist + S;                    // S
  int* blksum     = offs + S;                    // 1024
  int* blkoff     = blksum + 1024;               // 1024
  int2* ei2       = (int2*)(blkoff + 1024);      // E int2 (8B-aligned)
  size_t int_elems = (size_t)S * 2 + 2048 + (size_t)E * 2;
  int_elems = (int_elems + 3) & ~(size_t)3;      // 16B align
  ushort* WtH = (ushort*)(hist + int_elems);     // 1152*128
  ushort* WtL = WtH + 1152 * 128;                // 1152*128
  ushort* Y   = WtL + 1152 * 128;                // N*1152
  size_t ush_elems = 2 * 1152 * 128 + (size_t)N * 1152;
  ush_elems = (ush_elems + 1) & ~(size_t)1;      // float align
  float* t = (float*)(WtH + ush_elems);          // N*18

  hipMemsetAsync(hist, 0, sizeof(int) * (size_t)S, stream);

  k_hist<<<(E + 255) / 256, 256, 0, stream>>>(dst, et, hist, E);

  int NB = (S + 1023) / 1024;
  k_scan_local<<<NB, 256, 0, stream>>>(hist, offs, blksum, S);
  k_scan_blk<<<1, 512, 0, stream>>>(blksum, blkoff, NB);
  k_scan_add<<<NB, 256, 0, stream>>>(offs, blkoff, S);

  k_scatter_idx<<<(E + 255) / 256, 256, 0, stream>>>(src, dst, et, hist, offs, ei2, E);

  k_wsplit<<<1152, 128, 0, stream>>>(W1, Wr1, WtH, WtL);

  k_gemm_dense<<<(N + 63) / 64, 256, 0, stream>>>(x, WtH, WtL, Y, N);

  k_hgather<<<(N + 7) / 8, 256, 0, stream>>>(offs, hist, ei2, Y, b1, W2, Wr2, t, N);

  k_out2<<<(N + 31) / 32, 256, 0, stream>>>(offs, hist, ei2, t, b2, out, N);
}

// Round 25
// 249.241 us; speedup vs baseline: 1.2177x; 1.0244x over previous
//
#include <hip/hip_runtime.h>
#include <hip/hip_bf16.h>

// RGCN 2-layer forward. Transform-then-aggregate on BOTH layers.
// L1: Y[n,0:1152] = bf16(x[n]) @ [W_r0..W_r7 | Wroot]  (dense bf16 MFMA GEMM,
//     operand-swapped, r18 geometry, frozen at ~102us plateau).
// Sort: counting sort -> ei2[pos] = {src*8+rel, bits(1/cnt)} (mean folded/edge).
// hgather (this round): QUARTER-WAVE per node (16 nodes/block, 16 lanes x 8 cols,
//     uint4 loads), 8-deep pipeline -> 32 Y-loads in flight per wave;
//     fused layer-2 transform -> t[n,0:18].
// out2: 8 lanes/node (lane=relation), scale pre-folded.

#define NR 8
#define DH 128

typedef short short8 __attribute__((ext_vector_type(8)));
typedef float f32x4 __attribute__((ext_vector_type(4)));

__device__ inline ushort f2bf(float v) {
  __hip_bfloat16 b = __float2bfloat16(v);
  return *reinterpret_cast<ushort*>(&b);
}
__device__ inline float bf2f(ushort u) {
  __hip_bfloat16 b;
  *reinterpret_cast<ushort*>(&b) = u;
  return __bfloat162float(b);
}
__device__ inline uint pk2(float lo, float hi) {
  return (uint)f2bf(lo) | ((uint)f2bf(hi) << 16);
}
union U128 { uint4 u; short8 s; };
union FU { float f; int i; };

// ---------- counting sort ----------
__global__ __launch_bounds__(256) void k_hist(const int* __restrict__ dst, const int* __restrict__ et,
                                              int* __restrict__ hist, int E) {
  int e = blockIdx.x * 256 + threadIdx.x;
  if (e < E) atomicAdd(&hist[dst[e] * NR + et[e]], 1);
}

__global__ __launch_bounds__(256) void k_scan_local(const int* __restrict__ hist, int* __restrict__ offs,
                                                    int* __restrict__ blksum, int S) {
  __shared__ int tsum[256];
  int tid = threadIdx.x;
  int base = blockIdx.x * 1024 + tid * 4;
  int v[4], tot = 0;
  #pragma unroll
  for (int i = 0; i < 4; i++) { v[i] = (base + i < S) ? hist[base + i] : 0; tot += v[i]; }
  tsum[tid] = tot;
  __syncthreads();
  for (int off = 1; off < 256; off <<= 1) {
    int val = tsum[tid];
    int add = (tid >= off) ? tsum[tid - off] : 0;
    __syncthreads();
    tsum[tid] = val + add;
    __syncthreads();
  }
  int run = tsum[tid] - tot;
  #pragma unroll
  for (int i = 0; i < 4; i++) {
    if (base + i < S) offs[base + i] = run;
    run += v[i];
  }
  if (tid == 255) blksum[blockIdx.x] = tsum[255];
}

__global__ __launch_bounds__(512) void k_scan_blk(const int* __restrict__ blksum, int* __restrict__ blkoff, int NB) {
  __shared__ int s[512];
  int tid = threadIdx.x;
  int v = (tid < NB) ? blksum[tid] : 0;
  s[tid] = v;
  __syncthreads();
  for (int off = 1; off < 512; off <<= 1) {
    int val = s[tid];
    int add = (tid >= off) ? s[tid - off] : 0;
    __syncthreads();
    s[tid] = val + add;
    __syncthreads();
  }
  if (tid < NB) blkoff[tid] = s[tid] - v;
}

__global__ __launch_bounds__(256) void k_scan_add(int* __restrict__ offs, const int* __restrict__ blkoff, int S) {
  int tid = threadIdx.x;
  int base = blockIdx.x * 1024 + tid * 4;
  int add = blkoff[blockIdx.x];
  #pragma unroll
  for (int i = 0; i < 4; i++)
    if (base + i < S) offs[base + i] += add;
}

// scatter: ei2[pos] = {src*8+rel, bits(1/cnt)}; offs[seg] becomes segment END
__global__ __launch_bounds__(256) void k_scatter_idx(const int* __restrict__ src, const int* __restrict__ dst,
                                                     const int* __restrict__ et, const int* __restrict__ hist,
                                                     int* __restrict__ offs, int2* __restrict__ ei2, int E) {
  int e = blockIdx.x * 256 + threadIdx.x;
  if (e >= E) return;
  int r = et[e];
  int seg = dst[e] * NR + r;
  int pos = atomicAdd(&offs[seg], 1);
  FU sc;
  sc.f = 1.f / fmaxf((float)hist[seg], 1.f);
  ei2[pos] = make_int2(src[e] * NR + r, sc.i);
}

// ---------- W split+transpose: Wt[c][k], c in [0,1152), k in [0,128) ----------
__global__ __launch_bounds__(128) void k_wsplit(const float* __restrict__ W1, const float* __restrict__ Wr1,
                                                ushort* __restrict__ WtH, ushort* __restrict__ WtL) {
  int c = blockIdx.x;          // 0..1151
  int k = threadIdx.x;         // 0..127
  float v;
  if (c < 1024) {
    int r = c >> 7, col = c & 127;
    v = W1[((size_t)r * 128 + k) * 128 + col];
  } else {
    v = Wr1[(size_t)k * 128 + (c - 1024)];
  }
  ushort hi = f2bf(v);
  ushort lo = f2bf(v - bf2f(hi));
  WtH[(size_t)c * 128 + k] = hi;
  WtL[(size_t)c * 128 + k] = lo;
}

// ---------- dense GEMM: Y[N,1152] = bf16(x[N,128]) @ Wt^T, bf16 out (r18 exact) ----------
__global__ __launch_bounds__(256) void k_gemm_dense(
    const float* __restrict__ x,
    const ushort* __restrict__ WtH, const ushort* __restrict__ WtL,
    ushort* __restrict__ Y, int N) {
  int tid = threadIdx.x;
  int w = tid >> 6, lane = tid & 63;
  int n0 = blockIdx.x * 64;
  int wbase = w * 288;

  int frow = lane & 15;
  int fk8 = (lane >> 4) * 8;
  int q4 = (lane >> 4) * 4;

  int anode[4];
  bool nodeok[4];
  size_t ybase[4];
  #pragma unroll
  for (int nf = 0; nf < 4; nf++) {
    int n = n0 + nf * 16 + frow;
    nodeok[nf] = (n < N);
    anode[nf] = nodeok[nf] ? n : (N - 1);
    ybase[nf] = (size_t)anode[nf] * 1152 + q4;
  }

  uint4 xbr[4][4];
  #pragma unroll
  for (int nf = 0; nf < 4; nf++) {
    #pragma unroll
    for (int kc = 0; kc < 4; kc++) {
      const float4* xp = (const float4*)(x + (size_t)anode[nf] * 128 + kc * 32 + fk8);
      float4 v0 = xp[0], v1 = xp[1];
      uint4 o;
      o.x = pk2(v0.x, v0.y);
      o.y = pk2(v0.z, v0.w);
      o.z = pk2(v1.x, v1.y);
      o.w = pk2(v1.z, v1.w);
      xbr[nf][kc] = o;
    }
  }

  f32x4 acc[2][4];
  uint4 pw0[2][2], pw1[2][2];

  #define LOADW(P, CB, KC)                                                     \
    {                                                                          \
      _Pragma("unroll")                                                        \
      for (int cf = 0; cf < 2; cf++) {                                         \
        int c_ = (CB) + cf * 16 + frow;                                        \
        P[cf][0] = *(const uint4*)(WtH + (size_t)c_ * 128 + (KC) * 32 + fk8);  \
        P[cf][1] = *(const uint4*)(WtL + (size_t)c_ * 128 + (KC) * 32 + fk8);  \
      }                                                                        \
    }
  #define KSTEP(KC, PWU)                                                       \
    {                                                                          \
      _Pragma("unroll")                                                        \
      for (int cf = 0; cf < 2; cf++) {                                         \
        U128 wh_, wl_;                                                         \
        wh_.u = PWU[cf][0];                                                    \
        wl_.u = PWU[cf][1];                                                    \
        _Pragma("unroll")                                                      \
        for (int nf = 0; nf < 4; nf++) {                                       \
          U128 xv_;                                                            \
          xv_.u = xbr[nf][KC];                                                 \
          acc[cf][nf] = __builtin_amdgcn_mfma_f32_16x16x32_bf16(wh_.s, xv_.s, acc[cf][nf], 0, 0, 0); \
          acc[cf][nf] = __builtin_amdgcn_mfma_f32_16x16x32_bf16(wl_.s, xv_.s, acc[cf][nf], 0, 0, 0); \
        }                                                                      \
      }                                                                        \
    }
  #define CHUNK(CB, NCB, ISLAST)                                               \
    {                                                                          \
      _Pragma("unroll")                                                        \
      for (int cf = 0; cf < 2; cf++)                                           \
        _Pragma("unroll")                                                      \
        for (int nf = 0; nf < 4; nf++) acc[cf][nf] = (f32x4){0.f, 0.f, 0.f, 0.f}; \
      LOADW(pw1, CB, 1);                                                       \
      KSTEP(0, pw0);                                                           \
      LOADW(pw0, CB, 2);                                                       \
      KSTEP(1, pw1);                                                           \
      LOADW(pw1, CB, 3);                                                       \
      KSTEP(2, pw0);                                                           \
      if (!(ISLAST)) { LOADW(pw0, NCB, 0); }                                   \
      KSTEP(3, pw1);                                                           \
      _Pragma("unroll")                                                        \
      for (int cf = 0; cf < 2; cf++)                                           \
        _Pragma("unroll")                                                      \
        for (int nf = 0; nf < 4; nf++) {                                       \
          if (nodeok[nf]) {                                                    \
            ushort4 o_;                                                        \
            o_.x = f2bf(acc[cf][nf][0]);                                       \
            o_.y = f2bf(acc[cf][nf][1]);                                       \
            o_.z = f2bf(acc[cf][nf][2]);                                       \
            o_.w = f2bf(acc[cf][nf][3]);                                       \
            *(ushort4*)(Y + ybase[nf] + (CB) + cf * 16) = o_;                  \
          }                                                                    \
        }                                                                      \
    }

  LOADW(pw0, wbase, 0);

  CHUNK(wbase + 0,   wbase + 32,  0)
  CHUNK(wbase + 32,  wbase + 64,  0)
  CHUNK(wbase + 64,  wbase + 96,  0)
  CHUNK(wbase + 96,  wbase + 128, 0)
  CHUNK(wbase + 128, wbase + 160, 0)
  CHUNK(wbase + 160, wbase + 192, 0)
  CHUNK(wbase + 192, wbase + 224, 0)
  CHUNK(wbase + 224, wbase + 256, 0)
  CHUNK(wbase + 256, 0,           1)

  #undef LOADW
  #undef KSTEP
  #undef CHUNK
}

// ---------- fused h-gather + layer-2 transform: quarter-wave per node ----------
// 256 thr = 16 nodes/block; ql = tid&15 covers cols [ql*8, ql*8+8) (uint4).
// Flat edge loop 8-deep => 32 Y-loads in flight per wave (4 nodes).
__global__ __launch_bounds__(256) void k_hgather(const int* __restrict__ offs, const int* __restrict__ hist,
                                                 const int2* __restrict__ ei2, const ushort* __restrict__ Y,
                                                 const float* __restrict__ b1,
                                                 const float* __restrict__ W2, const float* __restrict__ Wr2,
                                                 float* __restrict__ t, int N) {
  __shared__ float Wt[18 * 128];
  int tid = threadIdx.x;
  for (int i = tid; i < 2304; i += 256) {
    float v; int oc, d;
    if (i < 2048) { int r = i >> 8, rem = i & 255; d = rem >> 1; int c = rem & 1; oc = r * 2 + c; v = W2[i]; }
    else { int i2 = i - 2048; d = i2 >> 1; int c = i2 & 1; oc = 16 + c; v = Wr2[i2]; }
    Wt[oc * 128 + d] = v;
  }
  __syncthreads();

  int node = blockIdx.x * 16 + (tid >> 4);
  int ql = tid & 15;
  if (node >= N) return;
  int c0 = ql * 8;
  int seg0 = node * NR;
  int st = offs[seg0] - hist[seg0];
  int en = offs[seg0 + 7];

  float a[8];
  {
    U128 vr;
    vr.u = *(const uint4*)(Y + (size_t)node * 1152 + 1024 + c0);
    float4 bb0 = *(const float4*)(b1 + c0);
    float4 bb1 = *(const float4*)(b1 + c0 + 4);
    a[0] = bf2f((ushort)vr.s[0]) + bb0.x;
    a[1] = bf2f((ushort)vr.s[1]) + bb0.y;
    a[2] = bf2f((ushort)vr.s[2]) + bb0.z;
    a[3] = bf2f((ushort)vr.s[3]) + bb0.w;
    a[4] = bf2f((ushort)vr.s[4]) + bb1.x;
    a[5] = bf2f((ushort)vr.s[5]) + bb1.y;
    a[6] = bf2f((ushort)vr.s[6]) + bb1.z;
    a[7] = bf2f((ushort)vr.s[7]) + bb1.w;
  }

  #define ACC8(V, SC)                                                          \
    {                                                                          \
      _Pragma("unroll")                                                        \
      for (int j = 0; j < 8; j++) a[j] += bf2f((ushort)(V).s[j]) * (SC);       \
    }

  int i = st;
  for (; i + 8 <= en; i += 8) {
    int2 e0 = ei2[i + 0];
    int2 e1 = ei2[i + 1];
    int2 e2 = ei2[i + 2];
    int2 e3 = ei2[i + 3];
    int2 e4 = ei2[i + 4];
    int2 e5 = ei2[i + 5];
    int2 e6 = ei2[i + 6];
    int2 e7 = ei2[i + 7];
    U128 v0, v1, v2, v3, v4, v5, v6, v7;
    v0.u = *(const uint4*)(Y + (((uint)(e0.x + (e0.x >> 3)) << 7) + c0));
    v1.u = *(const uint4*)(Y + (((uint)(e1.x + (e1.x >> 3)) << 7) + c0));
    v2.u = *(const uint4*)(Y + (((uint)(e2.x + (e2.x >> 3)) << 7) + c0));
    v3.u = *(const uint4*)(Y + (((uint)(e3.x + (e3.x >> 3)) << 7) + c0));
    v4.u = *(const uint4*)(Y + (((uint)(e4.x + (e4.x >> 3)) << 7) + c0));
    v5.u = *(const uint4*)(Y + (((uint)(e5.x + (e5.x >> 3)) << 7) + c0));
    v6.u = *(const uint4*)(Y + (((uint)(e6.x + (e6.x >> 3)) << 7) + c0));
    v7.u = *(const uint4*)(Y + (((uint)(e7.x + (e7.x >> 3)) << 7) + c0));
    FU s0, s1, s2, s3, s4, s5, s6, s7;
    s0.i = e0.y; s1.i = e1.y; s2.i = e2.y; s3.i = e3.y;
    s4.i = e4.y; s5.i = e5.y; s6.i = e6.y; s7.i = e7.y;
    ACC8(v0, s0.f); ACC8(v1, s1.f); ACC8(v2, s2.f); ACC8(v3, s3.f);
    ACC8(v4, s4.f); ACC8(v5, s5.f); ACC8(v6, s6.f); ACC8(v7, s7.f);
  }
  for (; i + 4 <= en; i += 4) {
    int2 e0 = ei2[i + 0];
    int2 e1 = ei2[i + 1];
    int2 e2 = ei2[i + 2];
    int2 e3 = ei2[i + 3];
    U128 v0, v1, v2, v3;
    v0.u = *(const uint4*)(Y + (((uint)(e0.x + (e0.x >> 3)) << 7) + c0));
    v1.u = *(const uint4*)(Y + (((uint)(e1.x + (e1.x >> 3)) << 7) + c0));
    v2.u = *(const uint4*)(Y + (((uint)(e2.x + (e2.x >> 3)) << 7) + c0));
    v3.u = *(const uint4*)(Y + (((uint)(e3.x + (e3.x >> 3)) << 7) + c0));
    FU s0, s1, s2, s3;
    s0.i = e0.y; s1.i = e1.y; s2.i = e2.y; s3.i = e3.y;
    ACC8(v0, s0.f); ACC8(v1, s1.f); ACC8(v2, s2.f); ACC8(v3, s3.f);
  }
  for (; i < en; i++) {
    int2 e = ei2[i];
    U128 v;
    v.u = *(const uint4*)(Y + (((uint)(e.x + (e.x >> 3)) << 7) + c0));
    FU sc; sc.i = e.y;
    ACC8(v, sc.f);
  }
  #undef ACC8

  float h[8];
  #pragma unroll
  for (int j = 0; j < 8; j++) h[j] = fmaxf(a[j], 0.f);

  #pragma unroll
  for (int oc = 0; oc < 18; oc++) {
    float4 wv0 = *(const float4*)(Wt + oc * 128 + c0);
    float4 wv1 = *(const float4*)(Wt + oc * 128 + c0 + 4);
    float p = h[0] * wv0.x + h[1] * wv0.y + h[2] * wv0.z + h[3] * wv0.w +
              h[4] * wv1.x + h[5] * wv1.y + h[6] * wv1.z + h[7] * wv1.w;
    p += __shfl_xor(p, 8);
    p += __shfl_xor(p, 4);
    p += __shfl_xor(p, 2);
    p += __shfl_xor(p, 1);
    if (ql == 0) t[(size_t)node * 18 + oc] = p;
  }
}

// ---------- output: 8 lanes per node (lane = relation), scale pre-folded ----------
__global__ __launch_bounds__(256) void k_out2(const int* __restrict__ offs, const int* __restrict__ hist,
                                              const int2* __restrict__ ei2, const float* __restrict__ t,
                                              const float* __restrict__ b2, float* __restrict__ out, int N) {
  int tid = threadIdx.x;
  int node = blockIdx.x * 32 + (tid >> 3);
  int r = tid & 7;
  if (node >= N) return;
  int seg = node * NR + r;
  int en = offs[seg];
  int cc = hist[seg];
  float s0 = 0.f, s1 = 0.f;
  for (int i = en - cc; i < en; i++) {
    int2 e = ei2[i];
    int src = e.x >> 3;
    FU sc; sc.i = e.y;
    float2 tv = *(const float2*)(t + (size_t)src * 18 + r * 2);
    s0 += tv.x * sc.f;
    s1 += tv.y * sc.f;
  }
  s0 += __shfl_xor(s0, 1); s1 += __shfl_xor(s1, 1);
  s0 += __shfl_xor(s0, 2); s1 += __shfl_xor(s1, 2);
  s0 += __shfl_xor(s0, 4); s1 += __shfl_xor(s1, 4);
  if (r == 0) {
    out[(size_t)node * 2 + 0] = s0 + t[(size_t)node * 18 + 16] + b2[0];
    out[(size_t)node * 2 + 1] = s1 + t[(size_t)node * 18 + 17] + b2[1];
  }
}

extern "C" void kernel_launch(void* const* d_in, const int* in_sizes, int n_in,
                              void* d_out, int out_size, void* d_ws, size_t ws_size,
                              hipStream_t stream) {
  const float* x   = (const float*)d_in[0];
  const int*   ei  = (const int*)d_in[1];
  const int*   et  = (const int*)d_in[2];
  const float* W1  = (const float*)d_in[3];
  const float* Wr1 = (const float*)d_in[4];
  const float* b1  = (const float*)d_in[5];
  const float* W2  = (const float*)d_in[6];
  const float* Wr2 = (const float*)d_in[7];
  const float* b2  = (const float*)d_in[8];
  float* out = (float*)d_out;

  int E = in_sizes[1] / 2;
  int N = in_sizes[0] / DH;
  int S = N * NR;
  const int* src = ei;
  const int* dst = ei + E;

  // ws layout: ints | ei2 (int2, E) | WtH WtL | Y (bf16, N*1152) | t
  int* hist       = (int*)d_ws;                  // S
  int* offs       = hist + S;                    // S
  int* blksum     = offs + S;                    // 1024
  int* blkoff     = blksum + 1024;               // 1024
  int2* ei2       = (int2*)(blkoff + 1024);      // E int2 (8B-aligned)
  size_t int_elems = (size_t)S * 2 + 2048 + (size_t)E * 2;
  int_elems = (int_elems + 3) & ~(size_t)3;      // 16B align
  ushort* WtH = (ushort*)(hist + int_elems);     // 1152*128
  ushort* WtL = WtH + 1152 * 128;                // 1152*128
  ushort* Y   = WtL + 1152 * 128;                // N*1152
  size_t ush_elems = 2 * 1152 * 128 + (size_t)N * 1152;
  ush_elems = (ush_elems + 1) & ~(size_t)1;      // float align
  float* t = (float*)(WtH + ush_elems);          // N*18

  hipMemsetAsync(hist, 0, sizeof(int) * (size_t)S, stream);

  k_hist<<<(E + 255) / 256, 256, 0, stream>>>(dst, et, hist, E);

  int NB = (S + 1023) / 1024;
  k_scan_local<<<NB, 256, 0, stream>>>(hist, offs, blksum, S);
  k_scan_blk<<<1, 512, 0, stream>>>(blksum, blkoff, NB);
  k_scan_add<<<NB, 256, 0, stream>>>(offs, blkoff, S);

  k_scatter_idx<<<(E + 255) / 256, 256, 0, stream>>>(src, dst, et, hist, offs, ei2, E);

  k_wsplit<<<1152, 128, 0, stream>>>(W1, Wr1, WtH, WtL);

  k_gemm_dense<<<(N + 63) / 64, 256, 0, stream>>>(x, WtH, WtL, Y, N);

  k_hgather<<<(N + 15) / 16, 256, 0, stream>>>(offs, hist, ei2, Y, b1, W2, Wr2, t, N);

  k_out2<<<(N + 31) / 32, 256, 0, stream>>>(offs, hist, ei2, t, b2, out, N);
}